// Round 10
// baseline (954.134 us; speedup 1.0000x reference)
//
#include <hip/hip_runtime.h>
#include <hip/hip_fp16.h>

#define TT 1024
#define BB 256
#define II 128
#define HH 256

typedef _Float16 h2 __attribute__((ext_vector_type(2)));

union HU { h2 h; unsigned u; };
static __device__ __forceinline__ h2 as_h2(unsigned v) { HU t; t.u = v; return t.h; }
static __device__ __forceinline__ unsigned pack2(float a, float b)
{
    HU t; t.h = h2{(_Float16)a, (_Float16)b}; return t.u;
}
static __device__ __forceinline__ float fdot2u(unsigned a, unsigned b, float c)
{
    return __builtin_amdgcn_fdot2(as_h2(a), as_h2(b), c, false);
}

// LDS-only barrier (h/x/pbuf handoff is pure LDS; global stores stay in flight).
#define LDS_BARRIER()                                            \
    do {                                                         \
        asm volatile("s_waitcnt lgkmcnt(0)" ::: "memory");       \
        __builtin_amdgcn_s_barrier();                            \
        __builtin_amdgcn_sched_barrier(0);                       \
    } while (0)

// tanh(a) = 1 - 2/(2^(2a*log2e)+1): v_exp_f32 + v_rcp_f32, err ~1e-6.
__device__ __forceinline__ float fast_tanh(float a)
{
    float e = __builtin_amdgcn_exp2f(a * 2.8853900817779268f);
    return 1.0f - 2.0f * __builtin_amdgcn_rcpf(e + 1.0f);
}

// One 1024-thread WG (16 waves -> 4 waves/SIMD) per batch row.
// R8 measured: issue ~1410 cyc/SIMD/step, total 2080 -> ~670 cyc stalled at
// 2 waves/SIMD. Total dot2 and readlane counts per SIMD are split-invariant
// (768 dot2-cyc + ~190 rl/mov-cyc), so 16-way split adds only ~100 cyc fixed
// overhead while 4-deep interleave compresses the stalls.
// Wave w owns K-slice w: k in [16w,16w+16) of V, [8w,8w+8) of W.
// Thread (lane l) owns outputs 4l..4l+3 -> Vreg[4][8]+Wreg[4][4] = 48 VGPRs.
// 16 partials reduce through pbuf; finalize in waves 0-3.
__global__ __launch_bounds__(1024, 1)
void rnn_splitk16(const float* __restrict__ x,
                  const float* __restrict__ W,
                  const float* __restrict__ bW,
                  const float* __restrict__ V,
                  const float* __restrict__ bV,
                  float* __restrict__ out)
{
    const int b   = blockIdx.x;
    const int tid = threadIdx.x;
    const int l   = tid & 63;
    // wave id as provably-uniform SGPR so readlane's index is uniform.
    const int w   = (__builtin_amdgcn_readfirstlane(tid) >> 6) & 15;
    const int lb  = 4 * w;  // lane base: pairs 8w..8w+7 live in lanes 4w..4w+3 (.x/.y)

    __shared__ __align__(16) _Float16 hbuf[HH];
    __shared__ __align__(16) _Float16 xbuf[II];
    __shared__ __align__(16) float    pbuf[16][HH];

    // Per-thread weights for 4 outputs x this wave's K-slice.
    unsigned Vreg[4][8];  // V[4l+c][16w + 2m, 2m+1], m=0..7
    unsigned Wreg[4][4];  // W[4l+c][8w + 2m, 2m+1],  m=0..3
#pragma unroll
    for (int c = 0; c < 4; ++c) {
        const int j = 4 * l + c;
        const float* vr = V + (size_t)j * HH + 16 * w;
#pragma unroll
        for (int m = 0; m < 8; ++m) Vreg[c][m] = pack2(vr[2 * m], vr[2 * m + 1]);
        const float* wr = W + (size_t)j * II + 8 * w;
#pragma unroll
        for (int m = 0; m < 4; ++m) Wreg[c][m] = pack2(wr[2 * m], wr[2 * m + 1]);
    }
    const float bias = (tid < HH) ? (bW[tid] + bV[tid]) : 0.f;

    if (tid < HH) hbuf[tid] = (_Float16)0.f;
    if (tid < II) xbuf[tid] = (_Float16)x[(size_t)b * II + tid];
    __syncthreads();

    float* __restrict__ seq = out;                         // (T,B,H) fp32
    float* __restrict__ fin = out + (size_t)TT * BB * HH;  // (B,H) fp32

    // Prologue X-phase: xsave = this wave's W-partials of x[0].
    float xsave[4] = {0.f, 0.f, 0.f, 0.f};
    {
        unsigned xv = reinterpret_cast<const unsigned*>(xbuf)[l];
#pragma unroll
        for (int i = 0; i < 4; ++i) {
            unsigned s = (unsigned)__builtin_amdgcn_readlane((int)xv, lb + i);
#pragma unroll
            for (int c = 0; c < 4; ++c) xsave[c] = fdot2u(s, Wreg[c][i], xsave[c]);
        }
    }
    // lane l holds h[4l..4l+3] as two packed pairs.
    uint2 hv = reinterpret_cast<const uint2*>(hbuf)[l];

    float xn = 0.f;
    if (tid < II && 1 < TT) xn = x[((size_t)1 * BB + b) * II + tid];

    float hf = 0.f;
#pragma unroll 1
    for (int t = 0; t < TT; ++t) {
        // ---- V phase: this wave's K-slice, 4 outputs (8 rl + 32 dot2) ----
        float va[4][2] = {{0.f,0.f},{0.f,0.f},{0.f,0.f},{0.f,0.f}};
#pragma unroll
        for (int i2 = 0; i2 < 4; ++i2) {
            unsigned s0 = (unsigned)__builtin_amdgcn_readlane((int)hv.x, lb + i2);
            unsigned s1 = (unsigned)__builtin_amdgcn_readlane((int)hv.y, lb + i2);
#pragma unroll
            for (int c = 0; c < 4; ++c) {
                va[c][0] = fdot2u(s0, Vreg[c][2 * i2],     va[c][0]);
                va[c][1] = fdot2u(s1, Vreg[c][2 * i2 + 1], va[c][1]);
            }
        }
        float4 tot;
        tot.x = va[0][0] + va[0][1] + xsave[0];
        tot.y = va[1][0] + va[1][1] + xsave[1];
        tot.z = va[2][0] + va[2][1] + xsave[2];
        tot.w = va[3][0] + va[3][1] + xsave[3];
        *reinterpret_cast<float4*>(&pbuf[w][4 * l]) = tot;  // contiguous b128

        // Stage x[t+1], issue load of x[t+2].
        if (t + 1 < TT && tid < II) xbuf[tid] = (_Float16)xn;
        float xn2 = 0.f;
        if (t + 2 < TT && tid < II) xn2 = x[((size_t)(t + 2) * BB + b) * II + tid];

        LDS_BARRIER();  // pbuf + xbuf visible

        // Finalizer partial reads (waves 0-3 only), issued early.
        float p[16];
        if (tid < HH) {
#pragma unroll
            for (int q = 0; q < 16; ++q) p[q] = pbuf[q][tid];
        }

        // ---- X phase for t+1 (all waves; hides pbuf read latency) ----
        if (t + 1 < TT) {
            unsigned xv = reinterpret_cast<const unsigned*>(xbuf)[l];
            xsave[0] = xsave[1] = xsave[2] = xsave[3] = 0.f;
#pragma unroll
            for (int i = 0; i < 4; ++i) {
                unsigned s = (unsigned)__builtin_amdgcn_readlane((int)xv, lb + i);
#pragma unroll
                for (int c = 0; c < 4; ++c) xsave[c] = fdot2u(s, Wreg[c][i], xsave[c]);
            }
        }

        // ---- finalize output `tid` (waves 0-3) ----
        if (tid < HH) {
            float r = ((((p[0] + p[1]) + (p[2] + p[3])) + ((p[4] + p[5]) + (p[6] + p[7]))) +
                       (((p[8] + p[9]) + (p[10] + p[11])) + ((p[12] + p[13]) + (p[14] + p[15])))) + bias;
            hf = fast_tanh(r);
            seq[((size_t)t * BB + b) * HH + tid] = hf;  // fire-and-forget
            hbuf[tid] = (_Float16)hf;
        }

        LDS_BARRIER();  // h(t) visible
        hv = reinterpret_cast<const uint2*>(hbuf)[l];
        xn = xn2;
    }
    if (tid < HH) fin[(size_t)b * HH + tid] = hf;
}

extern "C" void kernel_launch(void* const* d_in, const int* in_sizes, int n_in,
                              void* d_out, int out_size, void* d_ws, size_t ws_size,
                              hipStream_t stream)
{
    const float* x  = (const float*)d_in[0];
    const float* W  = (const float*)d_in[1];
    const float* bW = (const float*)d_in[2];
    const float* V  = (const float*)d_in[3];
    const float* bV = (const float*)d_in[4];
    float* out = (float*)d_out;

    rnn_splitk16<<<dim3(BB), dim3(1024), 0, stream>>>(x, W, bW, V, bV, out);
}